// Round 4
// baseline (28.909 us; speedup 1.0000x reference)
//
#include <hip/hip_runtime.h>

#define NQ 14

typedef float f2 __attribute__((ext_vector_type(2)));
typedef float f4 __attribute__((ext_vector_type(4)));

// cross-lane exchange with lane^1 via DPP quad_perm [1,0,3,2] (VALU, keeps LDS pipe free)
__device__ __forceinline__ float dpp_xor1(float v) {
  return __builtin_bit_cast(float,
      __builtin_amdgcn_mov_dpp(__builtin_bit_cast(int, v), 0xB1, 0xF, 0xF, true));
}

// ======== gates on 16 x f2 tile: reg bits b0..b3, elem = f2 lane, e = thread bit0 ========
template<int B>
__device__ __forceinline__ void ry_v(f2 (&v)[16], float c, float s) {
  const f2 cc = {c, c}, ss = {s, s};
#pragma unroll
  for (int j = 0; j < 16; ++j)
    if (!(j & (1 << B))) {
      f2 a = v[j], b = v[j | (1 << B)];
      v[j]            = a * cc - b * ss;
      v[j | (1 << B)] = a * ss + b * cc;
    }
}

__device__ __forceinline__ void ry_intra(f2 (&v)[16], float c, float s) {
  const f2 cc = {c, c}, ms = {-s, s};
#pragma unroll
  for (int j = 0; j < 16; ++j) {
    f2 sw = __builtin_shufflevector(v[j], v[j], 1, 0);
    v[j]  = v[j] * cc + sw * ms;
  }
}

// RY on the e-wire (thread bit0): partner via DPP; se = (lane odd) ? +s : -s
__device__ __forceinline__ void ry_e(f2 (&v)[16], float c, float se) {
  const f2 cc = {c, c}, ss = {se, se};
#pragma unroll
  for (int j = 0; j < 16; ++j) {
    f2 p; p.x = dpp_xor1(v[j].x); p.y = dpp_xor1(v[j].y);
    v[j] = v[j] * cc + p * ss;
  }
}

template<int CB, int TB>
__device__ __forceinline__ void cnot_v(f2 (&v)[16]) {
#pragma unroll
  for (int j = 0; j < 16; ++j)
    if ((j & (1 << CB)) && !(j & (1 << TB))) {
      f2 tmp = v[j]; v[j] = v[j | (1 << TB)]; v[j | (1 << TB)] = tmp;
    }
}

template<int TB>  // control = elem bit, target = reg bit TB
__device__ __forceinline__ void cnot_ic(f2 (&v)[16]) {
#pragma unroll
  for (int j = 0; j < 16; ++j)
    if (!(j & (1 << TB))) {
      float tmp = v[j].y; v[j].y = v[j | (1 << TB)].y; v[j | (1 << TB)].y = tmp;
    }
}

template<int CB>  // control = reg bit CB, target = e-wire (lane swap for those regs)
__device__ __forceinline__ void cnot_tgt_e(f2 (&v)[16]) {
#pragma unroll
  for (int j = 0; j < 16; ++j)
    if (j & (1 << CB)) { v[j].x = dpp_xor1(v[j].x); v[j].y = dpp_xor1(v[j].y); }
}

// control = e-wire, target = elem: odd lanes swap .x/.y of every f2
__device__ __forceinline__ void cnot_e_elem(f2 (&v)[16], bool hi) {
#pragma unroll
  for (int j = 0; j < 16; ++j) {
    f2 sw = __builtin_shufflevector(v[j], v[j], 1, 0);
    v[j] = hi ? sw : v[j];
  }
}

__device__ __forceinline__ void sc(float ang, float& s, float& c) {
  float th = 0.5f * ang; s = __sinf(th); c = __cosf(th);
}

// Config wire maps (wire w <-> role), 512 threads (t8..t0; e = t0, lanes t1..t5, waves t6..t8):
//  A : w0=b3 w1=b2 w2=b1 w3=b0 w4=e w5=elem   | thread wires: 6..13 on t8..t1
//  B1: w6=b3 w7=b2 w8=b1 w9=b0 w4=e w5=elem
//  C : w10=b3 w11=b2 w12=b1 w13=b0 w8=e w9=elem
//  B2: w6=b3 w7=b2 w4=b1 w5=b0 w8=e w9=elem
// Layouts L_AB / L_BC derived so every wave LDS instr is bank-conflict-free
// (A's b64s are a benign 4-way). See base formulas below; offsets are immediates.

__global__ __launch_bounds__(512) void vqc_kernel(const float* __restrict__ x,
                                                  const float* __restrict__ p,
                                                  float* __restrict__ out) {
  __shared__ float lds[16384];
  char* ldsb  = reinterpret_cast<char*>(lds);
  const int t  = threadIdx.x;
  const int b  = blockIdx.x;
  const bool hi = (t & 1);

#define TB_(k) ((t >> (k)) & 1)
  // L_AB bases (A in-place b64; B1 read b128; B2 write b128)
  const int baseA   = 8*TB_(5) + 16*TB_(1) + 32*TB_(2) + 576*TB_(3) + 128*TB_(4)
                    + 256*TB_(0) + 1024*TB_(6) + 2048*TB_(7) + 4096*TB_(8);
  const int baseB1r = 16*TB_(1) + 32*TB_(2) + 64*(TB_(3)^TB_(6)) + 128*TB_(7) + 256*TB_(0)
                    + 512*TB_(6) + 8192*TB_(4) + 16384*TB_(5) + 32768*TB_(8);
  const int baseB2w = 16*TB_(1) + 32*TB_(2) + 64*(TB_(3)^TB_(6)) + 128*TB_(7) + 1024*TB_(0)
                    + 512*TB_(6) + 8192*TB_(4) + 16384*TB_(5) + 32768*TB_(8);
  // L_BC bases (B1 write b64; C in-place b128; B2 read b64)
  const int baseB1w = 8*TB_(1) + 16*TB_(3) + 32*TB_(4) + 64*TB_(5) + 128*TB_(2) + 256*TB_(0)
                    + 2048*TB_(6) + 16384*TB_(7) + 32768*TB_(8);
  const int baseB2r = 8*TB_(1) + 16*TB_(3) + 32*TB_(4) + 64*TB_(5) + 128*TB_(2) + 512*TB_(0)
                    + 2048*TB_(6) + 16384*TB_(7) + 32768*TB_(8);
  const int baseC   = 16*TB_(1) + 32*TB_(2) + 64*TB_(3) + 512*TB_(0) + 1024*TB_(4)
                    + 4096*TB_(5) + 8192*TB_(6) + 256*TB_(7) + 32768*TB_(8);

  f2 loc[16];

#define RD_A()                                                                   \
  _Pragma("unroll") for (int j = 0; j < 16; ++j)                                 \
    loc[j] = *reinterpret_cast<const f2*>(ldsb + (((j & 1) ? (baseA ^ 64) : baseA) \
             + 8192*((j>>1)&1) + 16384*((j>>2)&1) + 32768*((j>>3)&1)));
#define WR_A()                                                                   \
  _Pragma("unroll") for (int j = 0; j < 16; ++j)                                 \
    *reinterpret_cast<f2*>(ldsb + (((j & 1) ? (baseA ^ 64) : baseA)              \
             + 8192*((j>>1)&1) + 16384*((j>>2)&1) + 32768*((j>>3)&1))) = loc[j];
#define RD_B1()                                                                  \
  _Pragma("unroll") for (int m = 0; m < 8; ++m) {                                \
    f4 v = *reinterpret_cast<const f4*>(ldsb + (baseB1r + 1024*(m&1)             \
             + 2048*((m>>1)&1) + 4096*((m>>2)&1)));                              \
    loc[2*m] = (f2){v.x, v.y}; loc[2*m+1] = (f2){v.z, v.w};                      \
  }
#define WR_B1()                                                                  \
  _Pragma("unroll") for (int n = 0; n < 16; ++n) {                               \
    const int e8 = n & 1, J = 2*(((n>>1)&1) + 2*((n>>2)&1) + 4*((n>>3)&1));      \
    f2 o = { e8 ? loc[J].y : loc[J].x, e8 ? loc[J+1].y : loc[J+1].x };           \
    *reinterpret_cast<f2*>(ldsb + (baseB1w + 8192*e8 + 512*((n>>1)&1)            \
             + 1024*((n>>2)&1) + 4096*((n>>3)&1))) = o;                          \
  }
#define RD_C()                                                                   \
  _Pragma("unroll") for (int m = 0; m < 8; ++m) {                                \
    f4 v = *reinterpret_cast<const f4*>(ldsb + (baseC + 128*(m&1)                \
             + 2048*((m>>1)&1) + 16384*((m>>2)&1)));                             \
    loc[2*m] = (f2){v.x, v.y}; loc[2*m+1] = (f2){v.z, v.w};                      \
  }
#define WR_C()                                                                   \
  _Pragma("unroll") for (int m = 0; m < 8; ++m) {                                \
    f4 v = {loc[2*m].x, loc[2*m].y, loc[2*m+1].x, loc[2*m+1].y};                 \
    *reinterpret_cast<f4*>(ldsb + (baseC + 128*(m&1)                             \
             + 2048*((m>>1)&1) + 16384*((m>>2)&1))) = v;                         \
  }
#define RD_B2()                                                                  \
  _Pragma("unroll") for (int j = 0; j < 16; ++j)                                 \
    loc[j] = *reinterpret_cast<const f2*>(ldsb + (baseB2r + 8192*(j&1)           \
             + 256*((j>>1)&1) + 1024*((j>>2)&1) + 4096*((j>>3)&1)));
#define WR_B2()                                                                  \
  _Pragma("unroll") for (int m = 0; m < 8; ++m) {                                \
    f4 v = {loc[2*m].x, loc[2*m+1].x, loc[2*m].y, loc[2*m+1].y};                 \
    *reinterpret_cast<f4*>(ldsb + (baseB2w + 256*(m&1)                           \
             + 2048*((m>>1)&1) + 4096*((m>>2)&1))) = v;                          \
  }

  // ================= P0: encoding+layer0 product state, layer0 A-CNOTs =================
  {
    float cw[NQ], sw[NQ];
#pragma unroll
    for (int q = 0; q < NQ; ++q) {
      float th = 0.5f * (x[b * NQ + q] + p[q]);
      sw[q] = __sinf(th); cw[q] = __cosf(th);
    }
    float P = 1.0f;
    P *= TB_(1) ? sw[13] : cw[13];
    P *= TB_(2) ? sw[12] : cw[12];
    P *= TB_(3) ? sw[11] : cw[11];
    P *= TB_(4) ? sw[10] : cw[10];
    P *= TB_(5) ? sw[9]  : cw[9];
    P *= TB_(6) ? sw[8]  : cw[8];
    P *= TB_(7) ? sw[7]  : cw[7];
    P *= TB_(8) ? sw[6]  : cw[6];
    P *= TB_(0) ? sw[4]  : cw[4];
    loc[0] = (f2){P * cw[5], P * sw[5]};
#pragma unroll
    for (int vb = 0; vb < 4; ++vb) {
      const int q = 3 - vb;
      const f2 cq = {cw[q], cw[q]}, sq = {sw[q], sw[q]};
#pragma unroll
      for (int m = 0; m < 16; ++m)
        if (m < (1 << vb)) {
          loc[m | (1 << vb)] = loc[m] * sq;
          loc[m]             = loc[m] * cq;
        }
    }
    // layer0 A-CNOTs: E(01) E(23) E(45), O(12) O(34)
    cnot_v<3, 2>(loc); cnot_v<1, 0>(loc); cnot_e_elem(loc, hi);
    cnot_v<2, 1>(loc); cnot_tgt_e<0>(loc);
    WR_A()
    __syncthreads();
  }

  // ================= main loop: B1, C(merged), B2, A(merged) =================
#pragma unroll 1
  for (int h = 0; h < 3; ++h) {
    const float* pa = p + 28 * h;   // layer 2h
    const float* pb = pa + 14;      // layer 2h+1
    float s, c;

    // ---- B1 (ABC layer 2h): RY6-9, E(67)(89), O(56)(78) ----
    RD_B1()
    if (h > 0) {
      sc(pa[6], s, c); ry_v<3>(loc, c, s);
      sc(pa[7], s, c); ry_v<2>(loc, c, s);
      sc(pa[8], s, c); ry_v<1>(loc, c, s);
      sc(pa[9], s, c); ry_v<0>(loc, c, s);
    }
    cnot_v<3, 2>(loc); cnot_v<1, 0>(loc);
    cnot_ic<3>(loc);   cnot_v<2, 1>(loc);
    __syncthreads();   // all L_AB reads complete before L_BC writes alias them
    WR_B1()
    __syncthreads();

    // ---- C merged (ABC layer 2h + CB'A layer 2h+1), in-place ----
    RD_C()
    if (h > 0) {
      sc(pa[10], s, c); ry_v<3>(loc, c, s);
      sc(pa[11], s, c); ry_v<2>(loc, c, s);
      sc(pa[12], s, c); ry_v<1>(loc, c, s);
      sc(pa[13], s, c); ry_v<0>(loc, c, s);
    }
    cnot_v<3, 2>(loc); cnot_v<1, 0>(loc);   // E(10,11) E(12,13)
    cnot_ic<3>(loc);   cnot_v<2, 1>(loc);   // O(9,10) O(11,12)
    sc(pb[8], s, c);  ry_e(loc, c, hi ? s : -s);
    sc(pb[9], s, c);  ry_intra(loc, c, s);
    sc(pb[10], s, c); ry_v<3>(loc, c, s);
    sc(pb[11], s, c); ry_v<2>(loc, c, s);
    sc(pb[12], s, c); ry_v<1>(loc, c, s);
    sc(pb[13], s, c); ry_v<0>(loc, c, s);
    cnot_e_elem(loc, hi);                   // E(89)
    cnot_v<3, 2>(loc); cnot_v<1, 0>(loc);   // E(10,11) E(12,13)
    cnot_ic<3>(loc);   cnot_v<2, 1>(loc);   // O(9,10) O(11,12)
    WR_C()
    __syncthreads();

    // ---- B2 (CB'A layer 2h+1): RY4-7, E(45)(67), O(56)(78) ----
    RD_B2()
    sc(pb[4], s, c); ry_v<1>(loc, c, s);
    sc(pb[5], s, c); ry_v<0>(loc, c, s);
    sc(pb[6], s, c); ry_v<3>(loc, c, s);
    sc(pb[7], s, c); ry_v<2>(loc, c, s);
    cnot_v<1, 0>(loc); cnot_v<3, 2>(loc);
    cnot_v<0, 3>(loc); cnot_tgt_e<2>(loc);
    __syncthreads();   // all L_BC reads complete before L_AB writes alias them
    WR_B2()
    __syncthreads();

    // ---- A merged (CB'A layer 2h+1 + ABC layer 2h+2), in-place ----
    if (h < 2) {
      const float* pc = pb + 14;  // layer 2h+2
      RD_A()
      sc(pb[0], s, c); ry_v<3>(loc, c, s);
      sc(pb[1], s, c); ry_v<2>(loc, c, s);
      sc(pb[2], s, c); ry_v<1>(loc, c, s);
      sc(pb[3], s, c); ry_v<0>(loc, c, s);
      cnot_v<3, 2>(loc); cnot_v<1, 0>(loc);   // E(01) E(23)
      cnot_v<2, 1>(loc); cnot_tgt_e<0>(loc);  // O(12) O(34)
      sc(pc[0], s, c); ry_v<3>(loc, c, s);
      sc(pc[1], s, c); ry_v<2>(loc, c, s);
      sc(pc[2], s, c); ry_v<1>(loc, c, s);
      sc(pc[3], s, c); ry_v<0>(loc, c, s);
      sc(pc[4], s, c); ry_e(loc, c, hi ? s : -s);
      sc(pc[5], s, c); ry_intra(loc, c, s);
      cnot_v<3, 2>(loc); cnot_v<1, 0>(loc); cnot_e_elem(loc, hi);  // E(01)(23)(45)
      cnot_v<2, 1>(loc); cnot_tgt_e<0>(loc);                       // O(12) O(34)
      WR_A()
      __syncthreads();
    }
  }

  // ================= P12: layer5 A-gates + <Z0> =================
  RD_A()
  {
    const float* p5 = p + 70;
    float s, c;
    sc(p5[0], s, c); ry_v<3>(loc, c, s);
    sc(p5[1], s, c); ry_v<2>(loc, c, s);
    sc(p5[2], s, c); ry_v<1>(loc, c, s);
    sc(p5[3], s, c); ry_v<0>(loc, c, s);
    cnot_v<3, 2>(loc); cnot_v<1, 0>(loc);
    cnot_v<2, 1>(loc); cnot_tgt_e<0>(loc);
  }
  // wire0 = reg bit3
  float acc = 0.f;
#pragma unroll
  for (int j = 0; j < 16; ++j) {
    float m = loc[j].x * loc[j].x + loc[j].y * loc[j].y;
    acc += (j & 8) ? -m : m;
  }
#pragma unroll
  for (int off = 32; off > 0; off >>= 1)
    acc += __shfl_down(acc, off, 64);
  __syncthreads();  // all state reads done; reuse LDS for partials
  if ((t & 63) == 0) lds[t >> 6] = acc;
  __syncthreads();
  if (t == 0) {
    float r = 0.f;
#pragma unroll
    for (int w = 0; w < 8; ++w) r += lds[w];
    out[b] = r;
  }
}

extern "C" void kernel_launch(void* const* d_in, const int* in_sizes, int n_in,
                              void* d_out, int out_size, void* d_ws, size_t ws_size,
                              hipStream_t stream) {
  const float* x   = (const float*)d_in[0];   // (BATCH, 14) float32
  const float* prm = (const float*)d_in[1];   // (84,)      float32
  float* out       = (float*)d_out;           // (BATCH,)   float32
  const int batch  = in_sizes[0] / NQ;        // 128
  if (batch <= 0) return;
  vqc_kernel<<<dim3(batch), dim3(512), 0, stream>>>(x, prm, out);
}

// Round 5
// 26.058 us; speedup vs baseline: 1.1094x; 1.1094x over previous
//
#include <hip/hip_runtime.h>

#define NQ 14

typedef float f2 __attribute__((ext_vector_type(2)));
typedef float f4 __attribute__((ext_vector_type(4)));

// ======== in-register gates on 32 x f2 tile (vec bits 0..4 = reg index, elem = f2 lane) ========
template<int B>
__device__ __forceinline__ void ry_v(f2 (&v)[32], float c, float s) {
  const f2 cc = {c, c}, ss = {s, s};
#pragma unroll
  for (int j = 0; j < 32; ++j)
    if (!(j & (1 << B))) {
      f2 a = v[j], b = v[j | (1 << B)];
      v[j]            = a * cc - b * ss;
      v[j | (1 << B)] = a * ss + b * cc;
    }
}

__device__ __forceinline__ void ry_intra(f2 (&v)[32], float c, float s) {
  const f2 cc = {c, c}, ms = {-s, s};
#pragma unroll
  for (int j = 0; j < 32; ++j) {
    f2 sw = __builtin_shufflevector(v[j], v[j], 1, 0);
    v[j]  = v[j] * cc + sw * ms;
  }
}

template<int CB, int TB>
__device__ __forceinline__ void cnot_v(f2 (&v)[32]) {
#pragma unroll
  for (int j = 0; j < 32; ++j)
    if ((j & (1 << CB)) && !(j & (1 << TB))) {
      f2 tmp = v[j]; v[j] = v[j | (1 << TB)]; v[j | (1 << TB)] = tmp;
    }
}

template<int CB>  // control = vec bit CB, target = elem bit
__device__ __forceinline__ void cnot_ci(f2 (&v)[32]) {
#pragma unroll
  for (int j = 0; j < 32; ++j)
    if (j & (1 << CB)) v[j] = __builtin_shufflevector(v[j], v[j], 1, 0);
}

template<int TB>  // control = elem bit, target = vec bit TB
__device__ __forceinline__ void cnot_ic(f2 (&v)[32]) {
#pragma unroll
  for (int j = 0; j < 32; ++j)
    if (!(j & (1 << TB))) {
      float tmp = v[j].y; v[j].y = v[j | (1 << TB)].y; v[j | (1 << TB)].y = tmp;
    }
}

// ======== LDS transfer: 16 x ds_read/write_b128, offsets are compile-time immediates ========
template<int STRIDE>
__device__ __forceinline__ void read_lin(f2 (&loc)[32], const char* ldsb, int base) {
#pragma unroll
  for (int r = 0; r < 16; ++r) {
    f4 v = *reinterpret_cast<const f4*>(ldsb + base + STRIDE * r);
    loc[2 * r]     = (f2){v.x, v.y};
    loc[2 * r + 1] = (f2){v.z, v.w};
  }
}
template<int STRIDE>
__device__ __forceinline__ void write_lin(const f2 (&loc)[32], char* ldsb, int base) {
#pragma unroll
  for (int r = 0; r < 16; ++r) {
    f4 v = {loc[2 * r].x, loc[2 * r].y, loc[2 * r + 1].x, loc[2 * r + 1].y};
    *reinterpret_cast<f4*>(ldsb + base + STRIDE * r) = v;
  }
}
// B'2 read of L_BC: quad index bits (r0,r1,r2,r3) -> byte mults (8192,16384,2048,4096)
__device__ __forceinline__ void read_b2(f2 (&loc)[32], const char* ldsb, int base) {
#pragma unroll
  for (int r = 0; r < 16; ++r) {
    const int off = 8192 * (r & 1) + 16384 * ((r >> 1) & 1) + 2048 * ((r >> 2) & 1) + 4096 * ((r >> 3) & 1);
    f4 v = *reinterpret_cast<const f4*>(ldsb + base + off);
    loc[2 * r]     = (f2){v.x, v.y};
    loc[2 * r + 1] = (f2){v.z, v.w};
  }
}
// B' gather-write: instr w = (k0,k1,k4,k5); block varies (k2,k3); j = k1+2k2+4k3+8k4+16k5, elem = k0
template<int M0, int M1, int M4, int M5>
__device__ __forceinline__ void write_gather(const f2 (&loc)[32], char* ldsb, int base) {
#pragma unroll
  for (int w = 0; w < 16; ++w) {
    const int k0 = w & 1, k1 = (w >> 1) & 1, k4 = (w >> 2) & 1, k5 = (w >> 3) & 1;
    const int jb = k1 + 8 * k4 + 16 * k5;
    f4 v = { k0 ? loc[jb].y     : loc[jb].x,
             k0 ? loc[jb + 2].y : loc[jb + 2].x,
             k0 ? loc[jb + 4].y : loc[jb + 4].x,
             k0 ? loc[jb + 6].y : loc[jb + 6].x };
    *reinterpret_cast<f4*>(ldsb + base + (M0 * k0 + M1 * k1 + M4 * k4 + M5 * k5)) = v;
  }
}

// ======== pass gate bodies; (s,c) pairs come from the LDS broadcast table ========
// tb points at this layer's 14 (s,c) entries. RY order within each group is
// commutation-reordered: half-local bits (3,2,1,0,intra) first, cross-half bit4 last,
// so gate math can start at lgkmcnt(8) while the upper-half state reads land.

__device__ __forceinline__ void gates_B1(f2 (&loc)[32], const f2* tb, bool withRY) {
  if (withRY) {  // RY wires 6..9
    f2 t6 = tb[6], t7 = tb[7], t8 = tb[8], t9 = tb[9];
    ry_v<3>(loc, t7.y, t7.x);
    ry_v<2>(loc, t8.y, t8.x);
    ry_v<1>(loc, t9.y, t9.x);
    ry_v<4>(loc, t6.y, t6.x);
  }
  cnot_v<4, 3>(loc);  // E(7,6)
  cnot_v<2, 1>(loc);  // E(5,4)
  cnot_ic<4>(loc);    // O(8,7)
  cnot_v<3, 2>(loc);  // O(6,5)
}

__device__ __forceinline__ void gates_B2(f2 (&loc)[32], const f2* tb) {
  f2 t4 = tb[4], t5 = tb[5], t6 = tb[6], t7 = tb[7];  // RY wires 4..7
  ry_v<2>(loc, t4.y, t4.x);
  ry_v<1>(loc, t5.y, t5.x);
  ry_v<3>(loc, t7.y, t7.x);
  ry_v<4>(loc, t6.y, t6.x);
  cnot_v<2, 1>(loc);  // E(9,8)
  cnot_v<4, 3>(loc);  // E(7,6)
  cnot_v<1, 4>(loc);  // O(8,7)
  cnot_v<3, 0>(loc);  // O(6,5)
}

__device__ __forceinline__ void gates_Cm(f2 (&loc)[32], const f2* ta, int lA) {
  const f2* tbp = ta + 14;
  if (lA > 0) {  // ABC-C RY wires 10..13
    f2 a10 = ta[10], a11 = ta[11], a12 = ta[12], a13 = ta[13];
    ry_v<3>(loc, a11.y, a11.x);
    ry_v<2>(loc, a12.y, a12.x);
    ry_v<1>(loc, a13.y, a13.x);
    ry_v<4>(loc, a10.y, a10.x);
  }
  cnot_v<4, 3>(loc);  // E(3,2)
  cnot_v<2, 1>(loc);  // E(1,0)
  cnot_ic<4>(loc);    // O(4,3)
  cnot_v<3, 2>(loc);  // O(2,1)
  // CB'A-C of layer lA+1: RY wires 8..13
  {
    f2 b8 = tbp[8], b9 = tbp[9], b10 = tbp[10], b11 = tbp[11], b12 = tbp[12], b13 = tbp[13];
    ry_v<0>(loc, b8.y, b8.x);
    ry_intra(loc, b9.y, b9.x);
    ry_v<3>(loc, b11.y, b11.x);
    ry_v<2>(loc, b12.y, b12.x);
    ry_v<1>(loc, b13.y, b13.x);
    ry_v<4>(loc, b10.y, b10.x);
  }
  cnot_ci<0>(loc);    // E(5,4)
  cnot_v<4, 3>(loc);  // E(3,2)
  cnot_v<2, 1>(loc);  // E(1,0)
  cnot_ic<4>(loc);    // O(4,3)
  cnot_v<3, 2>(loc);  // O(2,1)
}

__device__ __forceinline__ void gates_Am(f2 (&loc)[32], const f2* ta) {
  const f2* tbp = ta + 14;
  {  // CB'A-A of lA: RY wires 0..3
    f2 a0 = ta[0], a1 = ta[1], a2 = ta[2], a3 = ta[3];
    ry_v<3>(loc, a1.y, a1.x);
    ry_v<2>(loc, a2.y, a2.x);
    ry_v<1>(loc, a3.y, a3.x);
    ry_v<4>(loc, a0.y, a0.x);
  }
  cnot_v<4, 3>(loc);  // E(13,12)
  cnot_v<2, 1>(loc);  // E(11,10)
  cnot_v<3, 2>(loc);  // O(12,11)
  cnot_v<1, 0>(loc);  // O(10,9)
  {  // ABC-A of lA+1: RY wires 0..5
    f2 b0 = tbp[0], b1 = tbp[1], b2 = tbp[2], b3 = tbp[3], b4 = tbp[4], b5 = tbp[5];
    ry_v<3>(loc, b1.y, b1.x);
    ry_v<2>(loc, b2.y, b2.x);
    ry_v<1>(loc, b3.y, b3.x);
    ry_v<0>(loc, b4.y, b4.x);
    ry_intra(loc, b5.y, b5.x);
    ry_v<4>(loc, b0.y, b0.x);
  }
  cnot_v<4, 3>(loc);  // E(13,12)
  cnot_v<2, 1>(loc);  // E(11,10)
  cnot_ci<0>(loc);    // E(9,8)
  cnot_v<3, 2>(loc);  // O(12,11)
  cnot_v<1, 0>(loc);  // O(10,9)
}

__global__ __launch_bounds__(256) void vqc_kernel(const float* __restrict__ x,
                                                  const float* __restrict__ p,
                                                  float* __restrict__ out) {
  __shared__ float lds[16384];
  __shared__ f2 sctbl[96];  // 84 used: (sin, cos) of 0.5*angle per (layer, wire)
  char* ldsb  = reinterpret_cast<char*>(lds);
  const int t = threadIdx.x;
  const int b = blockIdx.x;

  // ---- build the (s,c) table once: thread t < 84 handles (layer t/14, wire t%14) ----
  if (t < 84) {
    float ang = p[t];
    if (t < 14) ang += x[b * NQ + t];  // layer-0 RY folds with encoding RY
    ang *= 0.5f;
    sctbl[t] = (f2){__sinf(ang), __cosf(ang)};
  }
  __syncthreads();

  // Per-pass LDS byte bases (pure bit-permutation layouts; offsets are immediates)
  const int bA   = 16 * t;
  const int bC   = 16 * (t & 7) + 2048 * ((t >> 3) & 7) + 16384 * (t >> 6);
  const int bBab = 16 * (t & 3) + 64 * ((t >> 4) & 1) + 128 * ((t >> 6) & 1) +
                   4096 * ((t >> 2) & 3) + 16384 * ((t >> 5) & 1) + 32768 * ((t >> 7) & 1);
  const int bBbc = 16 * ((t >> 2) & 3) + 64 * ((t >> 5) & 1) + 128 * (t & 3) +
                   512 * ((t >> 4) & 1) + 1024 * ((t >> 6) & 1) + 32768 * ((t >> 7) & 1);

  f2 loc[32];

  // ================= P0: composed product state + layer0 A-gates =================
  {
    float P = 1.0f;
#pragma unroll
    for (int q = 6; q < NQ; ++q) {
      f2 v = sctbl[q];
      P *= ((t >> (13 - q)) & 1) ? v.x : v.y;
    }
    // elem = wire5; v0..v4 = wires 4,3,2,1,0
    {
      f2 v5 = sctbl[5];
      loc[0] = (f2){P * v5.y, P * v5.x};
    }
#pragma unroll
    for (int vb = 0; vb < 5; ++vb) {
      f2 v = sctbl[4 - vb];
      const f2 cq = {v.y, v.y}, sq = {v.x, v.x};
#pragma unroll
      for (int m = 0; m < 32; ++m)
        if (m < (1 << vb)) {
          loc[m | (1 << vb)] = loc[m] * sq;
          loc[m]             = loc[m] * cq;
        }
    }
    cnot_v<4, 3>(loc);  // E(13,12)
    cnot_v<2, 1>(loc);  // E(11,10)
    cnot_ci<0>(loc);    // E(9,8)
    cnot_v<3, 2>(loc);  // O(12,11)
    cnot_v<1, 0>(loc);  // O(10,9)
    write_lin<4096>(loc, ldsb, bA);
    __syncthreads();
  }

  // ================= main merged-pass schedule =================
#pragma unroll 1
  for (int h = 0; h < 3; ++h) {
    const f2* tE = sctbl + 28 * h;   // layer 2h
    // B'1 pass (ABC layer 2h)
    read_lin<256>(loc, ldsb, bBab);
    gates_B1(loc, tE, h > 0);
    write_gather<8192, 16384, 2048, 4096>(loc, ldsb, bBbc);
    __syncthreads();
    // C merged pass (ABC layer 2h + CB'A layer 2h+1), in-place layout
    read_lin<128>(loc, ldsb, bC);
    gates_Cm(loc, tE, 2 * h);
    write_lin<128>(loc, ldsb, bC);
    __syncthreads();
    // B'2 pass (CB'A layer 2h+1)
    read_b2(loc, ldsb, bBbc);
    gates_B2(loc, tE + 14);
    write_gather<256, 512, 1024, 2048>(loc, ldsb, bBab);
    __syncthreads();
    // A merged pass (CB'A layer 2h+1 + ABC layer 2h+2), in-place layout
    if (h < 2) {
      read_lin<4096>(loc, ldsb, bA);
      gates_Am(loc, tE + 14);
      write_lin<4096>(loc, ldsb, bA);
      __syncthreads();
    }
  }

  // ================= P12: layer5 A-gates + measure <Z0> =================
  read_lin<4096>(loc, ldsb, bA);
  {
    const f2* t5 = sctbl + 70;
    f2 a0 = t5[0], a1 = t5[1], a2 = t5[2], a3 = t5[3];
    ry_v<3>(loc, a1.y, a1.x);
    ry_v<2>(loc, a2.y, a2.x);
    ry_v<1>(loc, a3.y, a3.x);
    ry_v<4>(loc, a0.y, a0.x);
    cnot_v<4, 3>(loc); cnot_v<2, 1>(loc);
    cnot_v<3, 2>(loc); cnot_v<1, 0>(loc);
  }
  // bit13 (wire 0) = reg bit 4
  float acc = 0.f;
#pragma unroll
  for (int j = 0; j < 32; ++j) {
    float m = loc[j].x * loc[j].x + loc[j].y * loc[j].y;
    acc += (j & 16) ? -m : m;
  }
#pragma unroll
  for (int off = 32; off > 0; off >>= 1)
    acc += __shfl_down(acc, off, 64);
  __syncthreads();  // all state reads done; reuse LDS for partials
  if ((t & 63) == 0) lds[t >> 6] = acc;
  __syncthreads();
  if (t == 0) out[b] = lds[0] + lds[1] + lds[2] + lds[3];
}

extern "C" void kernel_launch(void* const* d_in, const int* in_sizes, int n_in,
                              void* d_out, int out_size, void* d_ws, size_t ws_size,
                              hipStream_t stream) {
  const float* x   = (const float*)d_in[0];   // (BATCH, 14) float32
  const float* prm = (const float*)d_in[1];   // (84,)      float32
  float* out       = (float*)d_out;           // (BATCH,)   float32
  const int batch  = in_sizes[0] / NQ;        // 128
  if (batch <= 0) return;
  vqc_kernel<<<dim3(batch), dim3(256), 0, stream>>>(x, prm, out);
}

// Round 6
// 22.513 us; speedup vs baseline: 1.2841x; 1.1575x over previous
//
#include <hip/hip_runtime.h>

#define NQ 14

typedef float f2 __attribute__((ext_vector_type(2)));
typedef _Float16 h4 __attribute__((ext_vector_type(4)));
typedef _Float16 h8 __attribute__((ext_vector_type(8)));

// ======== in-register gates on 32 x f2 tile (reg bits v0..v4 = index bits, elem = f2 lane) ========
template<int B>
__device__ __forceinline__ void ry_v(f2 (&v)[32], float c, float s) {
  const f2 cc = {c, c}, ss = {s, s};
#pragma unroll
  for (int j = 0; j < 32; ++j)
    if (!(j & (1 << B))) {
      f2 a = v[j], b = v[j | (1 << B)];
      v[j]            = a * cc - b * ss;
      v[j | (1 << B)] = a * ss + b * cc;
    }
}

__device__ __forceinline__ void ry_intra(f2 (&v)[32], float c, float s) {
  const f2 cc = {c, c}, ms = {-s, s};
#pragma unroll
  for (int j = 0; j < 32; ++j) {
    f2 sw = __builtin_shufflevector(v[j], v[j], 1, 0);
    v[j]  = v[j] * cc + sw * ms;
  }
}

template<int CB, int TB>  // control = reg bit CB, target = reg bit TB
__device__ __forceinline__ void cnot_v(f2 (&v)[32]) {
#pragma unroll
  for (int j = 0; j < 32; ++j)
    if ((j & (1 << CB)) && !(j & (1 << TB))) {
      f2 tmp = v[j]; v[j] = v[j | (1 << TB)]; v[j | (1 << TB)] = tmp;
    }
}

template<int CB>  // control = reg bit CB, target = elem
__device__ __forceinline__ void cnot_ci(f2 (&v)[32]) {
#pragma unroll
  for (int j = 0; j < 32; ++j)
    if (j & (1 << CB)) v[j] = __builtin_shufflevector(v[j], v[j], 1, 0);
}

template<int TB>  // control = elem, target = reg bit TB
__device__ __forceinline__ void cnot_ic(f2 (&v)[32]) {
#pragma unroll
  for (int j = 0; j < 32; ++j)
    if (!(j & (1 << TB))) {
      float tmp = v[j].y; v[j].y = v[j | (1 << TB)].y; v[j | (1 << TB)].y = tmp;
    }
}

// ======== f16 LDS transfers. Amp a13..a0 (wire q <-> bit 13-q). Layouts verified end-to-end:
// Phi_AB(a) = 2a8+4a9+8a10 +16a0+32a1+64a2+128a3+256a4+512a5+1024a6+2048a7 +4096a11+8192a12+16384a13
// Phi_BC(a) = 2a4+4a5+8a3 +16(a10^a0)+32(a11^a1)+64(a12^a2) +128a0+256a1+512a2
//             +1024a6+2048a7+4096a8+8192a9 +16384a13
// A-pass threads: t_k=a_k(k=0..7); roles elem=a8(w5) v0=a9(w4) v1=a10(w3) v2=a11(w2) v3=a12(w1) v4=a13(w0)
// B-pass threads: t0..t2=a0..a2, t3..t5=a10..a12, t6=a3, t7=a13; roles elem=a8(w5) v0=a9(w4) v1=a4(w9) v2=a5(w8) v3=a6(w7) v4=a7(w6)
// C-pass threads: t0..t2=a10..a12, t3..t5=a6..a8, t6=a9, t7=a13; roles elem=a4(w9) v0=a5(w8) v1=a3(w10) v2=a2(w11) v3=a1(w12) v4=a0(w13)

__device__ __forceinline__ void rd_A(f2 (&loc)[32], const char* sb, int bA) {
#pragma unroll
  for (int r = 0; r < 8; ++r) {
    h8 v = *reinterpret_cast<const h8*>(sb + bA + 4096 * r);
#pragma unroll
    for (int i = 0; i < 4; ++i)
      loc[4 * r + i] = (f2){(float)v[2 * i], (float)v[2 * i + 1]};
  }
}
__device__ __forceinline__ void wr_A(const f2 (&loc)[32], char* sb, int bA) {
#pragma unroll
  for (int r = 0; r < 8; ++r) {
    h8 v;
#pragma unroll
    for (int i = 0; i < 4; ++i) {
      v[2 * i]     = (_Float16)loc[4 * r + i].x;
      v[2 * i + 1] = (_Float16)loc[4 * r + i].y;
    }
    *reinterpret_cast<h8*>(sb + bA + 4096 * r) = v;
  }
}
__device__ __forceinline__ void rd_BA(f2 (&loc)[32], const char* sb, int bBa) {
#pragma unroll
  for (int n = 0; n < 16; ++n) {
    h4 v = *reinterpret_cast<const h4*>(sb + bBa + 256 * n);
    loc[2 * n]     = (f2){(float)v[0], (float)v[1]};
    loc[2 * n + 1] = (f2){(float)v[2], (float)v[3]};
  }
}
__device__ __forceinline__ void wr_BA(const f2 (&loc)[32], char* sb, int bBa) {
#pragma unroll
  for (int n = 0; n < 16; ++n) {
    h4 v = {(_Float16)loc[2 * n].x, (_Float16)loc[2 * n].y,
            (_Float16)loc[2 * n + 1].x, (_Float16)loc[2 * n + 1].y};
    *reinterpret_cast<h4*>(sb + bBa + 256 * n) = v;
  }
}
// B-side access of L_BC: instr m = [a9 a8 a7 a6] -> offset 1024*m; chunk = (v2,v1); reg j = jb+4v2+2v1
__device__ __forceinline__ void wr_BC(const f2 (&loc)[32], char* sb, int bBc) {
#pragma unroll
  for (int m = 0; m < 16; ++m) {
    const int jb = 16 * ((m >> 1) & 1) + 8 * (m & 1) + ((m >> 3) & 1);
    const int e  = (m >> 2) & 1;
    h4 v = {(_Float16)(e ? loc[jb].y     : loc[jb].x),
            (_Float16)(e ? loc[jb + 2].y : loc[jb + 2].x),
            (_Float16)(e ? loc[jb + 4].y : loc[jb + 4].x),
            (_Float16)(e ? loc[jb + 6].y : loc[jb + 6].x)};
    *reinterpret_cast<h4*>(sb + bBc + 1024 * m) = v;
  }
}
__device__ __forceinline__ void rd_BC(f2 (&loc)[32], const char* sb, int bBc) {
#pragma unroll
  for (int m = 0; m < 16; ++m) {
    h4 v = *reinterpret_cast<const h4*>(sb + bBc + 1024 * m);
    const int jb = 16 * ((m >> 1) & 1) + 8 * (m & 1) + ((m >> 3) & 1);
    if ((m >> 2) & 1) {
      loc[jb].y = (float)v[0]; loc[jb + 2].y = (float)v[1];
      loc[jb + 4].y = (float)v[2]; loc[jb + 6].y = (float)v[3];
    } else {
      loc[jb].x = (float)v[0]; loc[jb + 2].x = (float)v[1];
      loc[jb + 4].x = (float)v[2]; loc[jb + 6].x = (float)v[3];
    }
  }
}
// C access of L_BC: instr r = [a2 a1 a0]; addr includes swizzle 16*((t&7)^r); reg block jb
__device__ __forceinline__ void rd_C(f2 (&loc)[32], const char* sb, int bC0, int tl) {
#pragma unroll
  for (int r = 0; r < 8; ++r) {
    const int jb = 16 * (r & 1) + 8 * ((r >> 1) & 1) + 4 * ((r >> 2) & 1);
    h8 v = *reinterpret_cast<const h8*>(sb + bC0 + 128 * r + ((tl ^ r) << 4));
#pragma unroll
    for (int i = 0; i < 4; ++i)
      loc[jb + i] = (f2){(float)v[2 * i], (float)v[2 * i + 1]};
  }
}
__device__ __forceinline__ void wr_C(const f2 (&loc)[32], char* sb, int bC0, int tl) {
#pragma unroll
  for (int r = 0; r < 8; ++r) {
    const int jb = 16 * (r & 1) + 8 * ((r >> 1) & 1) + 4 * ((r >> 2) & 1);
    h8 v;
#pragma unroll
    for (int i = 0; i < 4; ++i) {
      v[2 * i]     = (_Float16)loc[jb + i].x;
      v[2 * i + 1] = (_Float16)loc[jb + i].y;
    }
    *reinterpret_cast<h8*>(sb + bC0 + 128 * r + ((tl ^ r) << 4)) = v;
  }
}

__global__ __launch_bounds__(256) void vqc_kernel(const float* __restrict__ x,
                                                  const float* __restrict__ p,
                                                  float* __restrict__ out) {
  __shared__ _Float16 S[16384];   // 32 KB: L_AB and L_BC alias (reads drain before gate-delayed writes)
  __shared__ f2 sctbl[96];        // 84 used: (sin, cos) of 0.5*angle per (layer, wire)
  __shared__ float red[4];
  char* sb = reinterpret_cast<char*>(S);
  const int t = threadIdx.x;
  const int b = blockIdx.x;

  if (t < 84) {
    float ang = p[t];
    if (t < 14) ang += x[b * NQ + t];  // layer-0 RY folds with encoding RY
    ang *= 0.5f;
    sctbl[t] = (f2){__sinf(ang), __cosf(ang)};
  }
  __syncthreads();

  const int tl  = t & 7;
  const int bA  = 16 * t;
  const int bBa = 16 * (t & 7) + 8 * ((t >> 3) & 1) + 4096 * ((t >> 4) & 1) +
                  8192 * ((t >> 5) & 1) + 128 * ((t >> 6) & 1) + 16384 * ((t >> 7) & 1);
  const int bBc = 128 * (t & 7) + 16 * (((t >> 3) & 7) ^ (t & 7)) +
                  8 * ((t >> 6) & 1) + 16384 * ((t >> 7) & 1);
  const int bC0 = 1024 * ((t >> 3) & 7) + 8192 * ((t >> 6) & 1) + 16384 * ((t >> 7) & 1);

  f2 loc[32];

  // ================= P0: composed product state (enc + layer0 RYs) + layer0 A-part CNOTs ======
  {
    float P = 1.0f;
#pragma unroll
    for (int q = 6; q < NQ; ++q) {
      f2 v = sctbl[q];
      P *= ((t >> (13 - q)) & 1) ? v.x : v.y;
    }
    {
      f2 v5 = sctbl[5];
      loc[0] = (f2){P * v5.y, P * v5.x};
    }
#pragma unroll
    for (int vb = 0; vb < 5; ++vb) {
      f2 v = sctbl[4 - vb];  // wire 4-vb -> reg bit vb
      const f2 cq = {v.y, v.y}, sq = {v.x, v.x};
#pragma unroll
      for (int m = 0; m < 32; ++m)
        if (m < (1 << vb)) {
          loc[m | (1 << vb)] = loc[m] * sq;
          loc[m]             = loc[m] * cq;
        }
    }
    // A-part(l0): E(01) E(23) E(45), O(12) O(34)
    cnot_v<4, 3>(loc); cnot_v<2, 1>(loc); cnot_ci<0>(loc);
    cnot_v<3, 2>(loc); cnot_v<1, 0>(loc);
    wr_A(loc, sb, bA);
    __syncthreads();
  }

  // ================= main schedule: [B1, C-merged, B2, A-merged] x 3 =================
#pragma unroll 1
  for (int h = 0; h < 3; ++h) {
    const f2* tE = sctbl + 28 * h;  // layer 2h
    const f2* tO = tE + 14;         // layer 2h+1

    // ---- B1 (layer 2h): RY6-9; E(67) E(89); O(56) O(78) ----
    rd_BA(loc, sb, bBa);
    if (h > 0) {
      f2 r9 = tE[9], r8 = tE[8], r7 = tE[7], r6 = tE[6];
      ry_v<1>(loc, r9.y, r9.x);
      ry_v<2>(loc, r8.y, r8.x);
      ry_v<3>(loc, r7.y, r7.x);
      ry_v<4>(loc, r6.y, r6.x);
    }
    cnot_v<4, 3>(loc);  // E(6,7)
    cnot_v<2, 1>(loc);  // E(8,9)
    cnot_ic<4>(loc);    // O(5,6)
    cnot_v<3, 2>(loc);  // O(7,8)
    wr_BC(loc, sb, bBc);
    __syncthreads();

    // ---- C merged (layer 2h C-part + layer 2h+1 C-part), in-place ----
    rd_C(loc, sb, bC0, tl);
    if (h > 0) {
      f2 a10 = tE[10], a11 = tE[11], a12 = tE[12], a13 = tE[13];
      ry_v<1>(loc, a10.y, a10.x);
      ry_v<2>(loc, a11.y, a11.x);
      ry_v<3>(loc, a12.y, a12.x);
      ry_v<4>(loc, a13.y, a13.x);
    }
    cnot_v<1, 2>(loc);  // E(10,11)
    cnot_v<3, 4>(loc);  // E(12,13)
    cnot_ic<1>(loc);    // O(9,10)
    cnot_v<2, 3>(loc);  // O(11,12)
    {
      f2 b8 = tO[8], b9 = tO[9], b10 = tO[10], b11 = tO[11], b12 = tO[12], b13 = tO[13];
      ry_v<0>(loc, b8.y, b8.x);
      ry_intra(loc, b9.y, b9.x);
      ry_v<1>(loc, b10.y, b10.x);
      ry_v<2>(loc, b11.y, b11.x);
      ry_v<3>(loc, b12.y, b12.x);
      ry_v<4>(loc, b13.y, b13.x);
    }
    cnot_ci<0>(loc);    // E(8,9)
    cnot_v<1, 2>(loc);  // E(10,11)
    cnot_v<3, 4>(loc);  // E(12,13)
    cnot_ic<1>(loc);    // O(9,10)
    cnot_v<2, 3>(loc);  // O(11,12)
    wr_C(loc, sb, bC0, tl);
    __syncthreads();

    // ---- B2 (layer 2h+1): RY4-7; E(45) E(67); O(56) O(78) ----
    rd_BC(loc, sb, bBc);
    {
      f2 b4 = tO[4], b5 = tO[5], b6 = tO[6], b7 = tO[7];
      ry_v<0>(loc, b4.y, b4.x);
      ry_intra(loc, b5.y, b5.x);
      ry_v<3>(loc, b7.y, b7.x);
      ry_v<4>(loc, b6.y, b6.x);
    }
    cnot_ci<0>(loc);    // E(4,5)
    cnot_v<4, 3>(loc);  // E(6,7)
    cnot_ic<4>(loc);    // O(5,6)
    cnot_v<3, 2>(loc);  // O(7,8)
    wr_BA(loc, sb, bBa);
    __syncthreads();

    // ---- A merged (layer 2h+1 A-part + layer 2h+2 A-part), in-place ----
    if (h < 2) {
      const f2* tN = tO + 14;  // layer 2h+2
      rd_A(loc, sb, bA);
      {
        f2 a0 = tO[0], a1 = tO[1], a2 = tO[2], a3 = tO[3];
        ry_v<1>(loc, a3.y, a3.x);
        ry_v<2>(loc, a2.y, a2.x);
        ry_v<3>(loc, a1.y, a1.x);
        ry_v<4>(loc, a0.y, a0.x);
      }
      cnot_v<4, 3>(loc);  // E(0,1)
      cnot_v<2, 1>(loc);  // E(2,3)
      cnot_v<3, 2>(loc);  // O(1,2)
      cnot_v<1, 0>(loc);  // O(3,4)
      {
        f2 c0 = tN[0], c1 = tN[1], c2 = tN[2], c3 = tN[3], c4 = tN[4], c5 = tN[5];
        ry_v<0>(loc, c4.y, c4.x);
        ry_intra(loc, c5.y, c5.x);
        ry_v<1>(loc, c3.y, c3.x);
        ry_v<2>(loc, c2.y, c2.x);
        ry_v<3>(loc, c1.y, c1.x);
        ry_v<4>(loc, c0.y, c0.x);
      }
      cnot_v<4, 3>(loc);  // E(0,1)
      cnot_v<2, 1>(loc);  // E(2,3)
      cnot_ci<0>(loc);    // E(4,5)
      cnot_v<3, 2>(loc);  // O(1,2)
      cnot_v<1, 0>(loc);  // O(3,4)
      wr_A(loc, sb, bA);
      __syncthreads();
    }
  }

  // ================= final: layer5 A-part + measure <Z0> =================
  rd_A(loc, sb, bA);
  {
    const f2* t5 = sctbl + 70;
    f2 a0 = t5[0], a1 = t5[1], a2 = t5[2], a3 = t5[3];
    ry_v<1>(loc, a3.y, a3.x);
    ry_v<2>(loc, a2.y, a2.x);
    ry_v<3>(loc, a1.y, a1.x);
    ry_v<4>(loc, a0.y, a0.x);
    cnot_v<4, 3>(loc);  // E(0,1)
    cnot_v<2, 1>(loc);  // E(2,3)
    cnot_v<3, 2>(loc);  // O(1,2)
    cnot_v<1, 0>(loc);  // O(3,4)
  }
  // wire0 = reg bit 4
  float acc = 0.f;
#pragma unroll
  for (int j = 0; j < 32; ++j) {
    float m = loc[j].x * loc[j].x + loc[j].y * loc[j].y;
    acc += (j & 16) ? -m : m;
  }
#pragma unroll
  for (int off = 32; off > 0; off >>= 1)
    acc += __shfl_down(acc, off, 64);
  if ((t & 63) == 0) red[t >> 6] = acc;
  __syncthreads();
  if (t == 0) out[b] = red[0] + red[1] + red[2] + red[3];
}

extern "C" void kernel_launch(void* const* d_in, const int* in_sizes, int n_in,
                              void* d_out, int out_size, void* d_ws, size_t ws_size,
                              hipStream_t stream) {
  const float* x   = (const float*)d_in[0];   // (BATCH, 14) float32
  const float* prm = (const float*)d_in[1];   // (84,)      float32
  float* out       = (float*)d_out;           // (BATCH,)   float32
  const int batch  = in_sizes[0] / NQ;        // 128
  if (batch <= 0) return;
  vqc_kernel<<<dim3(batch), dim3(256), 0, stream>>>(x, prm, out);
}

// Round 7
// 19.854 us; speedup vs baseline: 1.4561x; 1.1339x over previous
//
#include <hip/hip_runtime.h>

#define NQ 14

typedef float f2 __attribute__((ext_vector_type(2)));
typedef float f4 __attribute__((ext_vector_type(4)));
typedef _Float16 h4 __attribute__((ext_vector_type(4)));
typedef _Float16 h8 __attribute__((ext_vector_type(8)));

// ======== in-register gates on 32 x f2 tile (reg bits v0..v4 = index bits, elem = f2 lane) ========
// Full-form RY (carries the pass's deferred scalar K): out = (C·a - S·b, S·a + C·b)
template<int B>
__device__ __forceinline__ void ry_v(f2 (&v)[32], float c, float s) {
  const f2 cc = {c, c}, ss = {s, s};
#pragma unroll
  for (int j = 0; j < 32; ++j)
    if (!(j & (1 << B))) {
      f2 a = v[j], b = v[j | (1 << B)];
      v[j]            = a * cc - b * ss;
      v[j | (1 << B)] = a * ss + b * cc;
    }
}
// Tangent-form RY: (I + t·J); the cos factor is deferred into the pass's full-form RY.
template<int B>
__device__ __forceinline__ void ry_vt(f2 (&v)[32], float t) {
  const f2 tp = {t, t}, tm = {-t, -t};
#pragma unroll
  for (int j = 0; j < 32; ++j)
    if (!(j & (1 << B))) {
      f2 a = v[j], b = v[j | (1 << B)];
      v[j]            = a + b * tm;   // 1 pk_fma
      v[j | (1 << B)] = b + a * tp;   // 1 pk_fma
    }
}
__device__ __forceinline__ void ry_intrat(f2 (&v)[32], float t) {
  const f2 mt = {-t, t};
#pragma unroll
  for (int j = 0; j < 32; ++j) {
    f2 sw = __builtin_shufflevector(v[j], v[j], 1, 0);
    v[j]  = v[j] + sw * mt;   // (a0 - t·a1, a1 + t·a0)
  }
}

template<int CB, int TB>  // control = reg bit CB, target = reg bit TB
__device__ __forceinline__ void cnot_v(f2 (&v)[32]) {
#pragma unroll
  for (int j = 0; j < 32; ++j)
    if ((j & (1 << CB)) && !(j & (1 << TB))) {
      f2 tmp = v[j]; v[j] = v[j | (1 << TB)]; v[j | (1 << TB)] = tmp;
    }
}
template<int CB>  // control = reg bit CB, target = elem
__device__ __forceinline__ void cnot_ci(f2 (&v)[32]) {
#pragma unroll
  for (int j = 0; j < 32; ++j)
    if (j & (1 << CB)) v[j] = __builtin_shufflevector(v[j], v[j], 1, 0);
}
template<int TB>  // control = elem, target = reg bit TB
__device__ __forceinline__ void cnot_ic(f2 (&v)[32]) {
#pragma unroll
  for (int j = 0; j < 32; ++j)
    if (!(j & (1 << TB))) {
      float tmp = v[j].y; v[j].y = v[j | (1 << TB)].y; v[j | (1 << TB)].y = tmp;
    }
}

// ======== f16 LDS transfers (layouts identical to R6, verified end-to-end) ========
__device__ __forceinline__ void rd_A(f2 (&loc)[32], const char* sb, int bA) {
#pragma unroll
  for (int r = 0; r < 8; ++r) {
    h8 v = *reinterpret_cast<const h8*>(sb + bA + 4096 * r);
#pragma unroll
    for (int i = 0; i < 4; ++i)
      loc[4 * r + i] = (f2){(float)v[2 * i], (float)v[2 * i + 1]};
  }
}
__device__ __forceinline__ void wr_A(const f2 (&loc)[32], char* sb, int bA) {
#pragma unroll
  for (int r = 0; r < 8; ++r) {
    h8 v;
#pragma unroll
    for (int i = 0; i < 4; ++i) {
      v[2 * i]     = (_Float16)loc[4 * r + i].x;
      v[2 * i + 1] = (_Float16)loc[4 * r + i].y;
    }
    *reinterpret_cast<h8*>(sb + bA + 4096 * r) = v;
  }
}
__device__ __forceinline__ void rd_BA(f2 (&loc)[32], const char* sb, int bBa) {
#pragma unroll
  for (int n = 0; n < 16; ++n) {
    h4 v = *reinterpret_cast<const h4*>(sb + bBa + 256 * n);
    loc[2 * n]     = (f2){(float)v[0], (float)v[1]};
    loc[2 * n + 1] = (f2){(float)v[2], (float)v[3]};
  }
}
__device__ __forceinline__ void wr_BA(const f2 (&loc)[32], char* sb, int bBa) {
#pragma unroll
  for (int n = 0; n < 16; ++n) {
    h4 v = {(_Float16)loc[2 * n].x, (_Float16)loc[2 * n].y,
            (_Float16)loc[2 * n + 1].x, (_Float16)loc[2 * n + 1].y};
    *reinterpret_cast<h4*>(sb + bBa + 256 * n) = v;
  }
}
__device__ __forceinline__ void wr_BC(const f2 (&loc)[32], char* sb, int bBc) {
#pragma unroll
  for (int m = 0; m < 16; ++m) {
    const int jb = 16 * ((m >> 1) & 1) + 8 * (m & 1) + ((m >> 3) & 1);
    const int e  = (m >> 2) & 1;
    h4 v = {(_Float16)(e ? loc[jb].y     : loc[jb].x),
            (_Float16)(e ? loc[jb + 2].y : loc[jb + 2].x),
            (_Float16)(e ? loc[jb + 4].y : loc[jb + 4].x),
            (_Float16)(e ? loc[jb + 6].y : loc[jb + 6].x)};
    *reinterpret_cast<h4*>(sb + bBc + 1024 * m) = v;
  }
}
__device__ __forceinline__ void rd_BC(f2 (&loc)[32], const char* sb, int bBc) {
#pragma unroll
  for (int m = 0; m < 16; ++m) {
    h4 v = *reinterpret_cast<const h4*>(sb + bBc + 1024 * m);
    const int jb = 16 * ((m >> 1) & 1) + 8 * (m & 1) + ((m >> 3) & 1);
    if ((m >> 2) & 1) {
      loc[jb].y = (float)v[0]; loc[jb + 2].y = (float)v[1];
      loc[jb + 4].y = (float)v[2]; loc[jb + 6].y = (float)v[3];
    } else {
      loc[jb].x = (float)v[0]; loc[jb + 2].x = (float)v[1];
      loc[jb + 4].x = (float)v[2]; loc[jb + 6].x = (float)v[3];
    }
  }
}
__device__ __forceinline__ void rd_C(f2 (&loc)[32], const char* sb, int bC0, int tl) {
#pragma unroll
  for (int r = 0; r < 8; ++r) {
    const int jb = 16 * (r & 1) + 8 * ((r >> 1) & 1) + 4 * ((r >> 2) & 1);
    h8 v = *reinterpret_cast<const h8*>(sb + bC0 + 128 * r + ((tl ^ r) << 4));
#pragma unroll
    for (int i = 0; i < 4; ++i)
      loc[jb + i] = (f2){(float)v[2 * i], (float)v[2 * i + 1]};
  }
}
__device__ __forceinline__ void wr_C(const f2 (&loc)[32], char* sb, int bC0, int tl) {
#pragma unroll
  for (int r = 0; r < 8; ++r) {
    const int jb = 16 * (r & 1) + 8 * ((r >> 1) & 1) + 4 * ((r >> 2) & 1);
    h8 v;
#pragma unroll
    for (int i = 0; i < 4; ++i) {
      v[2 * i]     = (_Float16)loc[jb + i].x;
      v[2 * i + 1] = (_Float16)loc[jb + i].y;
    }
    *reinterpret_cast<h8*>(sb + bC0 + 128 * r + ((tl ^ r) << 4)) = v;
  }
}

__global__ __launch_bounds__(256) void vqc_kernel(const float* __restrict__ x,
                                                  const float* __restrict__ p,
                                                  float* __restrict__ out) {
  __shared__ _Float16 S[16384];   // 32 KB: L_AB and L_BC alias (reads drain before gate-delayed writes)
  __shared__ f4 sctbl[96];        // 84 used: (tan, cos, sin, -) of 0.5*angle per (layer, wire)
  __shared__ float red[4];
  char* sb = reinterpret_cast<char*>(S);
  const int t = threadIdx.x;
  const int b = blockIdx.x;

  if (t < 84) {
    float ang = p[t];
    if (t < 14) ang += x[b * NQ + t];  // layer-0 RY folds with encoding RY
    ang *= 0.5f;
    float s = __sinf(ang), c = __cosf(ang);
    sctbl[t] = (f4){s / c, c, s, 0.f};
  }
  __syncthreads();

  const int tl  = t & 7;
  const int bA  = 16 * t;
  const int bBa = 16 * (t & 7) + 8 * ((t >> 3) & 1) + 4096 * ((t >> 4) & 1) +
                  8192 * ((t >> 5) & 1) + 128 * ((t >> 6) & 1) + 16384 * ((t >> 7) & 1);
  const int bBc = 128 * (t & 7) + 16 * (((t >> 3) & 7) ^ (t & 7)) +
                  8 * ((t >> 6) & 1) + 16384 * ((t >> 7) & 1);
  const int bC0 = 1024 * ((t >> 3) & 7) + 8192 * ((t >> 6) & 1) + 16384 * ((t >> 7) & 1);

  f2 loc[32];

  // ================= P0: composed product state (enc + layer0 RYs) + layer0 A-part CNOTs ======
  {
    float P = 1.0f;
#pragma unroll
    for (int q = 6; q < NQ; ++q) {
      f4 v = sctbl[q];
      P *= ((t >> (13 - q)) & 1) ? v.z : v.y;
    }
    {
      f4 v5 = sctbl[5];
      loc[0] = (f2){P * v5.y, P * v5.z};
    }
#pragma unroll
    for (int vb = 0; vb < 5; ++vb) {
      f4 v = sctbl[4 - vb];  // wire 4-vb -> reg bit vb
      const f2 cq = {v.y, v.y}, sq = {v.z, v.z};
#pragma unroll
      for (int m = 0; m < 32; ++m)
        if (m < (1 << vb)) {
          loc[m | (1 << vb)] = loc[m] * sq;
          loc[m]             = loc[m] * cq;
        }
    }
    // A-part(l0): E(01) E(23) E(45), O(12) O(34)
    cnot_v<4, 3>(loc); cnot_v<2, 1>(loc); cnot_ci<0>(loc);
    cnot_v<3, 2>(loc); cnot_v<1, 0>(loc);
    wr_A(loc, sb, bA);
    __syncthreads();
  }

  // ================= main schedule: [B1, C-merged, B2, A-merged] x 3 =================
#pragma unroll 1
  for (int h = 0; h < 3; ++h) {
    const f4* tE = sctbl + 28 * h;  // layer 2h
    const f4* tO = tE + 14;         // layer 2h+1

    // ---- B1 (layer 2h): RY6-9; E(67) E(89); O(56) O(78) ----
    rd_BA(loc, sb, bBa);
    if (h > 0) {
      f4 r9 = tE[9], r8 = tE[8], r7 = tE[7], r6 = tE[6];
      ry_vt<1>(loc, r9.x);
      ry_vt<2>(loc, r8.x);
      ry_vt<3>(loc, r7.x);
      float K = r9.y * r8.y * r7.y;
      ry_v<4>(loc, K * r6.y, K * r6.z);
    }
    cnot_v<4, 3>(loc);  // E(6,7)
    cnot_v<2, 1>(loc);  // E(8,9)
    cnot_ic<4>(loc);    // O(5,6)
    cnot_v<3, 2>(loc);  // O(7,8)
    wr_BC(loc, sb, bBc);
    __syncthreads();

    // ---- C merged (layer 2h C-part + layer 2h+1 C-part), in-place ----
    rd_C(loc, sb, bC0, tl);
    float KC = 1.f;
    if (h > 0) {
      f4 a10 = tE[10], a11 = tE[11], a12 = tE[12], a13 = tE[13];
      ry_vt<1>(loc, a10.x);
      ry_vt<2>(loc, a11.x);
      ry_vt<3>(loc, a12.x);
      ry_vt<4>(loc, a13.x);
      KC = a10.y * a11.y * a12.y * a13.y;
    }
    cnot_v<1, 2>(loc);  // E(10,11)
    cnot_v<3, 4>(loc);  // E(12,13)
    cnot_ic<1>(loc);    // O(9,10)
    cnot_v<2, 3>(loc);  // O(11,12)
    {
      f4 b8 = tO[8], b9 = tO[9], b10 = tO[10], b11 = tO[11], b12 = tO[12], b13 = tO[13];
      ry_vt<0>(loc, b8.x);
      ry_intrat(loc, b9.x);
      ry_vt<1>(loc, b10.x);
      ry_vt<2>(loc, b11.x);
      ry_vt<3>(loc, b12.x);
      KC *= b8.y * b9.y * b10.y * b11.y * b12.y;
      ry_v<4>(loc, KC * b13.y, KC * b13.z);
    }
    cnot_ci<0>(loc);    // E(8,9)
    cnot_v<1, 2>(loc);  // E(10,11)
    cnot_v<3, 4>(loc);  // E(12,13)
    cnot_ic<1>(loc);    // O(9,10)
    cnot_v<2, 3>(loc);  // O(11,12)
    wr_C(loc, sb, bC0, tl);
    __syncthreads();

    // ---- B2 (layer 2h+1): RY4-7; E(45) E(67); O(56) O(78) ----
    rd_BC(loc, sb, bBc);
    {
      f4 b4 = tO[4], b5 = tO[5], b6 = tO[6], b7 = tO[7];
      ry_vt<0>(loc, b4.x);
      ry_intrat(loc, b5.x);
      ry_vt<3>(loc, b7.x);
      float K = b4.y * b5.y * b7.y;
      ry_v<4>(loc, K * b6.y, K * b6.z);
    }
    cnot_ci<0>(loc);    // E(4,5)
    cnot_v<4, 3>(loc);  // E(6,7)
    cnot_ic<4>(loc);    // O(5,6)
    cnot_v<3, 2>(loc);  // O(7,8)
    wr_BA(loc, sb, bBa);
    __syncthreads();

    // ---- A merged (layer 2h+1 A-part + layer 2h+2 A-part), in-place ----
    if (h < 2) {
      const f4* tN = tO + 14;  // layer 2h+2
      rd_A(loc, sb, bA);
      float KA;
      {
        f4 a0 = tO[0], a1 = tO[1], a2 = tO[2], a3 = tO[3];
        ry_vt<1>(loc, a3.x);
        ry_vt<2>(loc, a2.x);
        ry_vt<3>(loc, a1.x);
        ry_vt<4>(loc, a0.x);
        KA = a3.y * a2.y * a1.y * a0.y;
      }
      cnot_v<4, 3>(loc);  // E(0,1)
      cnot_v<2, 1>(loc);  // E(2,3)
      cnot_v<3, 2>(loc);  // O(1,2)
      cnot_v<1, 0>(loc);  // O(3,4)
      {
        f4 c0 = tN[0], c1 = tN[1], c2 = tN[2], c3 = tN[3], c4 = tN[4], c5 = tN[5];
        ry_vt<0>(loc, c4.x);
        ry_intrat(loc, c5.x);
        ry_vt<1>(loc, c3.x);
        ry_vt<2>(loc, c2.x);
        ry_vt<3>(loc, c1.x);
        KA *= c4.y * c5.y * c3.y * c2.y * c1.y;
        ry_v<4>(loc, KA * c0.y, KA * c0.z);
      }
      cnot_v<4, 3>(loc);  // E(0,1)
      cnot_v<2, 1>(loc);  // E(2,3)
      cnot_ci<0>(loc);    // E(4,5)
      cnot_v<3, 2>(loc);  // O(1,2)
      cnot_v<1, 0>(loc);  // O(3,4)
      wr_A(loc, sb, bA);
      __syncthreads();
    }
  }

  // ================= final: layer5 A-part + measure <Z0> =================
  rd_A(loc, sb, bA);
  {
    const f4* t5 = sctbl + 70;
    f4 a0 = t5[0], a1 = t5[1], a2 = t5[2], a3 = t5[3];
    ry_vt<1>(loc, a3.x);
    ry_vt<2>(loc, a2.x);
    ry_vt<3>(loc, a1.x);
    float K = a3.y * a2.y * a1.y;
    ry_v<4>(loc, K * a0.y, K * a0.z);
    cnot_v<4, 3>(loc);  // E(0,1)
    cnot_v<2, 1>(loc);  // E(2,3)
    cnot_v<3, 2>(loc);  // O(1,2)
    cnot_v<1, 0>(loc);  // O(3,4)
  }
  // wire0 = reg bit 4
  float acc = 0.f;
#pragma unroll
  for (int j = 0; j < 32; ++j) {
    float m = loc[j].x * loc[j].x + loc[j].y * loc[j].y;
    acc += (j & 16) ? -m : m;
  }
#pragma unroll
  for (int off = 32; off > 0; off >>= 1)
    acc += __shfl_down(acc, off, 64);
  if ((t & 63) == 0) red[t >> 6] = acc;
  __syncthreads();
  if (t == 0) out[b] = red[0] + red[1] + red[2] + red[3];
}

extern "C" void kernel_launch(void* const* d_in, const int* in_sizes, int n_in,
                              void* d_out, int out_size, void* d_ws, size_t ws_size,
                              hipStream_t stream) {
  const float* x   = (const float*)d_in[0];   // (BATCH, 14) float32
  const float* prm = (const float*)d_in[1];   // (84,)      float32
  float* out       = (float*)d_out;           // (BATCH,)   float32
  const int batch  = in_sizes[0] / NQ;        // 128
  if (batch <= 0) return;
  vqc_kernel<<<dim3(batch), dim3(256), 0, stream>>>(x, prm, out);
}

// Round 9
// 19.816 us; speedup vs baseline: 1.4589x; 1.0019x over previous
//
#include <hip/hip_runtime.h>

#define NQ 14

typedef float f2 __attribute__((ext_vector_type(2)));
typedef float f4 __attribute__((ext_vector_type(4)));
typedef _Float16 h2 __attribute__((ext_vector_type(2)));
typedef _Float16 h4 __attribute__((ext_vector_type(4)));
typedef _Float16 h8 __attribute__((ext_vector_type(8)));

__device__ __forceinline__ h2 pk2(float a, float b) {
  return __builtin_bit_cast(h2, __builtin_amdgcn_cvt_pkrtz(a, b));
}

// ======== in-register gates on 32 x f2 tile (reg bits v0..v4 = index bits, elem = f2 lane) ========
// Tangent-form RY: (I + t·J). The cos factors of ALL 70 in-loop RYs are deferred into
// one global scalar K; the final observable is multiplied by K^2.
template<int B>
__device__ __forceinline__ void ry_vt(f2 (&v)[32], float t) {
  const f2 tp = {t, t}, tm = {-t, -t};
#pragma unroll
  for (int j = 0; j < 32; ++j)
    if (!(j & (1 << B))) {
      f2 a = v[j], b = v[j | (1 << B)];
      v[j]            = a + b * tm;   // 1 pk_fma
      v[j | (1 << B)] = b + a * tp;   // 1 pk_fma
    }
}
__device__ __forceinline__ void ry_intrat(f2 (&v)[32], float t) {
  const f2 mt = {-t, t};
#pragma unroll
  for (int j = 0; j < 32; ++j) {
    f2 sw = __builtin_shufflevector(v[j], v[j], 1, 0);
    v[j]  = v[j] + sw * mt;   // (a0 - t·a1, a1 + t·a0)
  }
}

template<int CB, int TB>  // control = reg bit CB, target = reg bit TB
__device__ __forceinline__ void cnot_v(f2 (&v)[32]) {
#pragma unroll
  for (int j = 0; j < 32; ++j)
    if ((j & (1 << CB)) && !(j & (1 << TB))) {
      f2 tmp = v[j]; v[j] = v[j | (1 << TB)]; v[j | (1 << TB)] = tmp;
    }
}
template<int CB>  // control = reg bit CB, target = elem
__device__ __forceinline__ void cnot_ci(f2 (&v)[32]) {
#pragma unroll
  for (int j = 0; j < 32; ++j)
    if (j & (1 << CB)) v[j] = __builtin_shufflevector(v[j], v[j], 1, 0);
}
template<int TB>  // control = elem, target = reg bit TB
__device__ __forceinline__ void cnot_ic(f2 (&v)[32]) {
#pragma unroll
  for (int j = 0; j < 32; ++j)
    if (!(j & (1 << TB))) {
      float tmp = v[j].y; v[j].y = v[j | (1 << TB)].y; v[j | (1 << TB)].y = tmp;
    }
}

// ======== f16 LDS transfers (layouts identical to R6/R7, verified end-to-end) ========
__device__ __forceinline__ void rd_A(f2 (&loc)[32], const char* sb, int bA) {
#pragma unroll
  for (int r = 0; r < 8; ++r) {
    h8 v = *reinterpret_cast<const h8*>(sb + bA + 4096 * r);
#pragma unroll
    for (int i = 0; i < 4; ++i)
      loc[4 * r + i] = (f2){(float)v[2 * i], (float)v[2 * i + 1]};
  }
}
__device__ __forceinline__ void wr_A(const f2 (&loc)[32], char* sb, int bA) {
#pragma unroll
  for (int r = 0; r < 8; ++r) {
    h2 p0 = pk2(loc[4 * r].x,     loc[4 * r].y);
    h2 p1 = pk2(loc[4 * r + 1].x, loc[4 * r + 1].y);
    h2 p2 = pk2(loc[4 * r + 2].x, loc[4 * r + 2].y);
    h2 p3 = pk2(loc[4 * r + 3].x, loc[4 * r + 3].y);
    h4 a = __builtin_shufflevector(p0, p1, 0, 1, 2, 3);
    h4 b = __builtin_shufflevector(p2, p3, 0, 1, 2, 3);
    *reinterpret_cast<h8*>(sb + bA + 4096 * r) =
        __builtin_shufflevector(a, b, 0, 1, 2, 3, 4, 5, 6, 7);
  }
}
__device__ __forceinline__ void rd_BA(f2 (&loc)[32], const char* sb, int bBa) {
#pragma unroll
  for (int n = 0; n < 16; ++n) {
    h4 v = *reinterpret_cast<const h4*>(sb + bBa + 256 * n);
    loc[2 * n]     = (f2){(float)v[0], (float)v[1]};
    loc[2 * n + 1] = (f2){(float)v[2], (float)v[3]};
  }
}
__device__ __forceinline__ void wr_BA(const f2 (&loc)[32], char* sb, int bBa) {
#pragma unroll
  for (int n = 0; n < 16; ++n) {
    h2 p0 = pk2(loc[2 * n].x,     loc[2 * n].y);
    h2 p1 = pk2(loc[2 * n + 1].x, loc[2 * n + 1].y);
    *reinterpret_cast<h4*>(sb + bBa + 256 * n) =
        __builtin_shufflevector(p0, p1, 0, 1, 2, 3);
  }
}
__device__ __forceinline__ void wr_BC(const f2 (&loc)[32], char* sb, int bBc) {
#pragma unroll
  for (int m = 0; m < 16; ++m) {
    const int jb = 16 * ((m >> 1) & 1) + 8 * (m & 1) + ((m >> 3) & 1);
    const int e  = (m >> 2) & 1;
    h2 p0 = pk2(e ? loc[jb].y     : loc[jb].x,     e ? loc[jb + 2].y : loc[jb + 2].x);
    h2 p1 = pk2(e ? loc[jb + 4].y : loc[jb + 4].x, e ? loc[jb + 6].y : loc[jb + 6].x);
    *reinterpret_cast<h4*>(sb + bBc + 1024 * m) =
        __builtin_shufflevector(p0, p1, 0, 1, 2, 3);
  }
}
__device__ __forceinline__ void rd_BC(f2 (&loc)[32], const char* sb, int bBc) {
#pragma unroll
  for (int m = 0; m < 16; ++m) {
    h4 v = *reinterpret_cast<const h4*>(sb + bBc + 1024 * m);
    const int jb = 16 * ((m >> 1) & 1) + 8 * (m & 1) + ((m >> 3) & 1);
    if ((m >> 2) & 1) {
      loc[jb].y = (float)v[0]; loc[jb + 2].y = (float)v[1];
      loc[jb + 4].y = (float)v[2]; loc[jb + 6].y = (float)v[3];
    } else {
      loc[jb].x = (float)v[0]; loc[jb + 2].x = (float)v[1];
      loc[jb + 4].x = (float)v[2]; loc[jb + 6].x = (float)v[3];
    }
  }
}
__device__ __forceinline__ void rd_C(f2 (&loc)[32], const char* sb, int bC0, int tl) {
#pragma unroll
  for (int r = 0; r < 8; ++r) {
    const int jb = 16 * (r & 1) + 8 * ((r >> 1) & 1) + 4 * ((r >> 2) & 1);
    h8 v = *reinterpret_cast<const h8*>(sb + bC0 + 128 * r + ((tl ^ r) << 4));
#pragma unroll
    for (int i = 0; i < 4; ++i)
      loc[jb + i] = (f2){(float)v[2 * i], (float)v[2 * i + 1]};
  }
}
__device__ __forceinline__ void wr_C(const f2 (&loc)[32], char* sb, int bC0, int tl) {
#pragma unroll
  for (int r = 0; r < 8; ++r) {
    const int jb = 16 * (r & 1) + 8 * ((r >> 1) & 1) + 4 * ((r >> 2) & 1);
    h2 p0 = pk2(loc[jb].x,     loc[jb].y);
    h2 p1 = pk2(loc[jb + 1].x, loc[jb + 1].y);
    h2 p2 = pk2(loc[jb + 2].x, loc[jb + 2].y);
    h2 p3 = pk2(loc[jb + 3].x, loc[jb + 3].y);
    h4 a = __builtin_shufflevector(p0, p1, 0, 1, 2, 3);
    h4 b = __builtin_shufflevector(p2, p3, 0, 1, 2, 3);
    *reinterpret_cast<h8*>(sb + bC0 + 128 * r + ((tl ^ r) << 4)) =
        __builtin_shufflevector(a, b, 0, 1, 2, 3, 4, 5, 6, 7);
  }
}

__global__ __launch_bounds__(256) void vqc_kernel(const float* __restrict__ x,
                                                  const float* __restrict__ p,
                                                  float* __restrict__ out) {
  __shared__ _Float16 S[16384];   // 32 KB: L_AB and L_BC alias (reads drain before gate-delayed writes)
  __shared__ f4 sctbl[96];        // 84 used: (tan, cos, sin, -) of 0.5*angle per (layer, wire)
  __shared__ float red[4];
  char* sb = reinterpret_cast<char*>(S);
  const int t = threadIdx.x;
  const int b = blockIdx.x;

  if (t < 84) {
    float ang = p[t];
    if (t < 14) ang += x[b * NQ + t];  // layer-0 RY folds with encoding RY
    ang *= 0.5f;
    float s = __sinf(ang), c = __cosf(ang);
    sctbl[t] = (f4){s / c, c, s, 0.f};
  }
  __syncthreads();

  // K = prod of cos over layers 1..5 (sctbl[14..83], 70 values).
  // Wave 0 butterfly covers [14..77]; thread 0 multiplies the 6-value tail [78..83].
  // Only thread 0's kv is ever consumed (it also writes out[b]) -> no extra sync needed.
  float kv = 1.f;
  if (t < 64) {
    kv = sctbl[14 + t].y;
#pragma unroll
    for (int off = 32; off; off >>= 1) kv *= __shfl_xor(kv, off, 64);
    if (t == 0) {
#pragma unroll
      for (int i = 78; i < 84; ++i) kv *= sctbl[i].y;
    }
  }

  const int tl  = t & 7;
  const int bA  = 16 * t;
  const int bBa = 16 * (t & 7) + 8 * ((t >> 3) & 1) + 4096 * ((t >> 4) & 1) +
                  8192 * ((t >> 5) & 1) + 128 * ((t >> 6) & 1) + 16384 * ((t >> 7) & 1);
  const int bBc = 128 * (t & 7) + 16 * (((t >> 3) & 7) ^ (t & 7)) +
                  8 * ((t >> 6) & 1) + 16384 * ((t >> 7) & 1);
  const int bC0 = 1024 * ((t >> 3) & 7) + 8192 * ((t >> 6) & 1) + 16384 * ((t >> 7) & 1);

  f2 loc[32];

  // ================= P0: composed product state (enc + layer0 RYs) + layer0 A-part CNOTs ======
  {
    float P = 1.0f;
#pragma unroll
    for (int q = 6; q < NQ; ++q) {
      f4 v = sctbl[q];
      P *= ((t >> (13 - q)) & 1) ? v.z : v.y;
    }
    {
      f4 v5 = sctbl[5];
      loc[0] = (f2){P * v5.y, P * v5.z};
    }
#pragma unroll
    for (int vb = 0; vb < 5; ++vb) {
      f4 v = sctbl[4 - vb];  // wire 4-vb -> reg bit vb
      const f2 cq = {v.y, v.y}, sq = {v.z, v.z};
#pragma unroll
      for (int m = 0; m < 32; ++m)
        if (m < (1 << vb)) {
          loc[m | (1 << vb)] = loc[m] * sq;
          loc[m]             = loc[m] * cq;
        }
    }
    // A-part(l0): E(01) E(23) E(45), O(12) O(34)
    cnot_v<4, 3>(loc); cnot_v<2, 1>(loc); cnot_ci<0>(loc);
    cnot_v<3, 2>(loc); cnot_v<1, 0>(loc);
    wr_A(loc, sb, bA);
    __syncthreads();
  }

  // ================= main schedule: [B1, C-merged, B2, A-merged] x 3 =================
#pragma unroll 1
  for (int h = 0; h < 3; ++h) {
    const f4* tE = sctbl + 28 * h;  // layer 2h
    const f4* tO = tE + 14;         // layer 2h+1

    // ---- B1 (layer 2h): RY6-9; E(67) E(89); O(56) O(78) ----
    rd_BA(loc, sb, bBa);
    if (h > 0) {
      ry_vt<1>(loc, tE[9].x);
      ry_vt<2>(loc, tE[8].x);
      ry_vt<3>(loc, tE[7].x);
      ry_vt<4>(loc, tE[6].x);
    }
    cnot_v<4, 3>(loc);  // E(6,7)
    cnot_v<2, 1>(loc);  // E(8,9)
    cnot_ic<4>(loc);    // O(5,6)
    cnot_v<3, 2>(loc);  // O(7,8)
    wr_BC(loc, sb, bBc);
    __syncthreads();

    // ---- C merged (layer 2h C-part + layer 2h+1 C-part), in-place ----
    rd_C(loc, sb, bC0, tl);
    if (h > 0) {
      ry_vt<1>(loc, tE[10].x);
      ry_vt<2>(loc, tE[11].x);
      ry_vt<3>(loc, tE[12].x);
      ry_vt<4>(loc, tE[13].x);
    }
    cnot_v<1, 2>(loc);  // E(10,11)
    cnot_v<3, 4>(loc);  // E(12,13)
    cnot_ic<1>(loc);    // O(9,10)
    cnot_v<2, 3>(loc);  // O(11,12)
    ry_vt<0>(loc, tO[8].x);
    ry_intrat(loc, tO[9].x);
    ry_vt<1>(loc, tO[10].x);
    ry_vt<2>(loc, tO[11].x);
    ry_vt<3>(loc, tO[12].x);
    ry_vt<4>(loc, tO[13].x);
    cnot_ci<0>(loc);    // E(8,9)
    cnot_v<1, 2>(loc);  // E(10,11)
    cnot_v<3, 4>(loc);  // E(12,13)
    cnot_ic<1>(loc);    // O(9,10)
    cnot_v<2, 3>(loc);  // O(11,12)
    wr_C(loc, sb, bC0, tl);
    __syncthreads();

    // ---- B2 (layer 2h+1): RY4-7; E(45) E(67); O(56) O(78) ----
    rd_BC(loc, sb, bBc);
    ry_vt<0>(loc, tO[4].x);
    ry_intrat(loc, tO[5].x);
    ry_vt<3>(loc, tO[7].x);
    ry_vt<4>(loc, tO[6].x);
    cnot_ci<0>(loc);    // E(4,5)
    cnot_v<4, 3>(loc);  // E(6,7)
    cnot_ic<4>(loc);    // O(5,6)
    cnot_v<3, 2>(loc);  // O(7,8)
    wr_BA(loc, sb, bBa);
    __syncthreads();

    // ---- A merged (layer 2h+1 A-part + layer 2h+2 A-part), in-place ----
    if (h < 2) {
      const f4* tN = tO + 14;  // layer 2h+2
      rd_A(loc, sb, bA);
      ry_vt<1>(loc, tO[3].x);
      ry_vt<2>(loc, tO[2].x);
      ry_vt<3>(loc, tO[1].x);
      ry_vt<4>(loc, tO[0].x);
      cnot_v<4, 3>(loc);  // E(0,1)
      cnot_v<2, 1>(loc);  // E(2,3)
      cnot_v<3, 2>(loc);  // O(1,2)
      cnot_v<1, 0>(loc);  // O(3,4)
      ry_vt<0>(loc, tN[4].x);
      ry_intrat(loc, tN[5].x);
      ry_vt<1>(loc, tN[3].x);
      ry_vt<2>(loc, tN[2].x);
      ry_vt<3>(loc, tN[1].x);
      ry_vt<4>(loc, tN[0].x);
      cnot_v<4, 3>(loc);  // E(0,1)
      cnot_v<2, 1>(loc);  // E(2,3)
      cnot_ci<0>(loc);    // E(4,5)
      cnot_v<3, 2>(loc);  // O(1,2)
      cnot_v<1, 0>(loc);  // O(3,4)
      wr_A(loc, sb, bA);
      __syncthreads();
    }
  }

  // ================= final: layer5 A-part + measure <Z0> =================
  rd_A(loc, sb, bA);
  {
    const f4* t5 = sctbl + 70;
    ry_vt<1>(loc, t5[3].x);
    ry_vt<2>(loc, t5[2].x);
    ry_vt<3>(loc, t5[1].x);
    ry_vt<4>(loc, t5[0].x);
    cnot_v<4, 3>(loc);  // E(0,1)
    cnot_v<2, 1>(loc);  // E(2,3)
    cnot_v<3, 2>(loc);  // O(1,2)
    cnot_v<1, 0>(loc);  // O(3,4)
  }
  // wire0 = reg bit 4
  float acc = 0.f;
#pragma unroll
  for (int j = 0; j < 32; ++j) {
    float m = loc[j].x * loc[j].x + loc[j].y * loc[j].y;
    acc += (j & 16) ? -m : m;
  }
#pragma unroll
  for (int off = 32; off > 0; off >>= 1)
    acc += __shfl_down(acc, off, 64);
  if ((t & 63) == 0) red[t >> 6] = acc;
  __syncthreads();
  if (t == 0) out[b] = (kv * kv) * (red[0] + red[1] + red[2] + red[3]);
}

extern "C" void kernel_launch(void* const* d_in, const int* in_sizes, int n_in,
                              void* d_out, int out_size, void* d_ws, size_t ws_size,
                              hipStream_t stream) {
  const float* x   = (const float*)d_in[0];   // (BATCH, 14) float32
  const float* prm = (const float*)d_in[1];   // (84,)      float32
  float* out       = (float*)d_out;           // (BATCH,)   float32
  const int batch  = in_sizes[0] / NQ;        // 128
  if (batch <= 0) return;
  vqc_kernel<<<dim3(batch), dim3(256), 0, stream>>>(x, prm, out);
}